// Round 1
// baseline (1039.332 us; speedup 1.0000x reference)
//
#include <hip/hip_runtime.h>

// UnivariateTripleMLP: out[j] = relu(relu(x_j @ W1 + b1) @ W2 + b2) @ W3 + b3
// where x_j = inputs[:, j], inputs is [1024, 131072] row-major fp32.
//
// Layer 1 dominates (17.2 GFLOP). Strategy: thread-per-column.
//  - inputs loads: lane j reads inputs[k*BA + j] -> perfectly coalesced.
//  - W1 loads: address depends only on uniform loop counters -> s_load
//    (scalar cache), consumed as the SGPR operand of v_fmac_f32.
//  - k-loop unrolled x8 with the 8 loads hoisted ahead of the 512 FMAs
//    to keep 8 global loads in flight per wave (grid gives only 2
//    waves/SIMD, so ILP must cover HBM latency).

#define RC 1024
#define BA 131072
#define D1 64
#define D2 16
#define KU 8

__global__ __launch_bounds__(256) void mlp3_kernel(
    const float* __restrict__ inputs,
    const float* __restrict__ W1,
    const float* __restrict__ b1,
    const float* __restrict__ W2,
    const float* __restrict__ b2,
    const float* __restrict__ W3,
    const float* __restrict__ b3,
    float* __restrict__ out)
{
    const int j = blockIdx.x * blockDim.x + threadIdx.x;
    const float* __restrict__ col = inputs + j;

    float acc[D1];
#pragma unroll
    for (int d = 0; d < D1; ++d) acc[d] = 0.0f;

    for (int k0 = 0; k0 < RC; k0 += KU) {
        float x[KU];
#pragma unroll
        for (int u = 0; u < KU; ++u)
            x[u] = col[(k0 + u) * BA];
#pragma unroll
        for (int u = 0; u < KU; ++u) {
#pragma unroll
            for (int d = 0; d < D1; ++d)
                acc[d] = fmaf(x[u], W1[(k0 + u) * D1 + d], acc[d]);
        }
    }

    // Layer 2: h2 = relu(h1 @ W2 + b2), W2 is [64,16] row-major (uniform scalar reads)
    float h2[D2];
#pragma unroll
    for (int e = 0; e < D2; ++e) h2[e] = b2[e];
#pragma unroll
    for (int d = 0; d < D1; ++d) {
        float h = acc[d] + b1[d];
        h = h > 0.0f ? h : 0.0f;
#pragma unroll
        for (int e = 0; e < D2; ++e)
            h2[e] = fmaf(h, W2[d * D2 + e], h2[e]);
    }

    // Layer 3: out = relu(h2) @ W3 + b3
    float o = b3[0];
#pragma unroll
    for (int e = 0; e < D2; ++e) {
        float h = h2[e] > 0.0f ? h2[e] : 0.0f;
        o = fmaf(h, W3[e], o);
    }
    out[j] = o;
}

extern "C" void kernel_launch(void* const* d_in, const int* in_sizes, int n_in,
                              void* d_out, int out_size, void* d_ws, size_t ws_size,
                              hipStream_t stream) {
    const float* inputs = (const float*)d_in[0];
    const float* W1     = (const float*)d_in[1];
    const float* b1     = (const float*)d_in[2];
    const float* W2     = (const float*)d_in[3];
    const float* b2     = (const float*)d_in[4];
    const float* W3     = (const float*)d_in[5];
    const float* b3     = (const float*)d_in[6];
    float* out = (float*)d_out;

    dim3 block(256);
    dim3 grid(BA / 256);  // 512 blocks, one thread per output column
    mlp3_kernel<<<grid, block, 0, stream>>>(inputs, W1, b1, W2, b2, W3, b3, out);
}

// Round 2
// 685.014 us; speedup vs baseline: 1.5172x; 1.5172x over previous
//
#include <hip/hip_runtime.h>

// Layer-1 as f16 MFMA GEMM: C[M=131072, N=64] = inputs^T[M,K=1024] @ W1[K,64]
// inputs is [K, M] row-major (m-contiguous -> coalesced staging loads).
// Per block: 256 threads = 4 waves; M_block=128 (one 32-row tile per wave),
// N=64 (2 n-tiles of 32), K chunked by 64 through LDS (f16, k-contiguous,
// stride 72 to balance banks; b128 frags).
// Epilogue: acc -> LDS [m][n] -> per-column fp32 layers 2+3 -> out.

#define RC 1024
#define BA 131072
#define D1 64
#define D2 16

#define MB  128           // m per block
#define KC  64            // k per chunk
#define NCH (RC / KC)     // 16 chunks
#define KS  72            // padded k-stride (f16) for A/W tiles
#define HS  68            // padded n-stride (f32) for h1 tile

using f16x8  = __attribute__((ext_vector_type(8))) _Float16;
using f32x16 = __attribute__((ext_vector_type(16))) float;

__global__ __launch_bounds__(256, 4) void mlp3_mfma(
    const float* __restrict__ inputs,
    const float* __restrict__ W1,
    const float* __restrict__ b1,
    const float* __restrict__ W2,
    const float* __restrict__ b2,
    const float* __restrict__ W3,
    const float* __restrict__ b3,
    float* __restrict__ out)
{
    // staging: A [128][72] f16 (18432 B) + W [64][72] f16 (9216 B) = 27648 B
    // epilogue: H [4][32][68] f32 = 34816 B (aliases staging, barrier-protected)
    __shared__ __align__(16) _Float16 smem[17408];
    _Float16* Ash = smem;
    _Float16* Wsh = smem + MB * KS;
    float*    Hsh = (float*)smem;

    const int t    = threadIdx.x;
    const int lane = t & 63;
    const int wave = t >> 6;

    const int mA  = t & (MB - 1);  // A-staging: column index
    const int kgA = t >> 7;        // A-staging: k-octet group (0..1)
    const int nW  = t & 63;        // W-staging: n index
    const int kgW = t >> 6;        // W-staging: k-octet group (0..3)

    f32x16 acc0 = {};
    f32x16 acc1 = {};

    const int mBase = blockIdx.x * MB;
    const float* Aptr = inputs + mBase + mA;

    for (int c = 0; c < NCH; ++c) {
        const int k0 = c * KC;
        if (c) __syncthreads();  // WAR: previous chunk's frag reads done

        // ---- stage A chunk: m=mA, k = k0 + s*16 + kgA*8 + {0..7} ----
        #pragma unroll
        for (int s = 0; s < 4; ++s) {
            const int kl = s * 16 + kgA * 8;
            float xv[8];
            #pragma unroll
            for (int u = 0; u < 8; ++u)
                xv[u] = Aptr[(size_t)(k0 + kl + u) * BA];
            f16x8 h;
            #pragma unroll
            for (int u = 0; u < 8; ++u) h[u] = (_Float16)xv[u];
            *(f16x8*)(Ash + mA * KS + kl) = h;
        }
        // ---- stage W1 chunk: n=nW, k = k0 + s2*32 + kgW*8 + {0..7} ----
        #pragma unroll
        for (int s2 = 0; s2 < 2; ++s2) {
            const int kl = s2 * 32 + kgW * 8;
            float wv[8];
            #pragma unroll
            for (int u = 0; u < 8; ++u)
                wv[u] = W1[(size_t)(k0 + kl + u) * D1 + nW];
            f16x8 h;
            #pragma unroll
            for (int u = 0; u < 8; ++u) h[u] = (_Float16)wv[u];
            *(f16x8*)(Wsh + nW * KS + kl) = h;
        }
        __syncthreads();

        // ---- MFMA over 4 k-steps of 16 ----
        const int mf = wave * 32 + (lane & 31);
        const int kf = (lane >> 5) * 8;
        #pragma unroll
        for (int ks = 0; ks < 4; ++ks) {
            f16x8 a  = *(const f16x8*)(Ash + mf * KS + ks * 16 + kf);
            f16x8 b0f = *(const f16x8*)(Wsh + (lane & 31) * KS + ks * 16 + kf);
            f16x8 b1f = *(const f16x8*)(Wsh + ((lane & 31) + 32) * KS + ks * 16 + kf);
            acc0 = __builtin_amdgcn_mfma_f32_32x32x16_f16(a, b0f, acc0, 0, 0, 0);
            acc1 = __builtin_amdgcn_mfma_f32_32x32x16_f16(a, b1f, acc1, 0, 0, 0);
        }
    }
    __syncthreads();  // staging region about to be overwritten by H tile

    // ---- spill h1 tile: C/D layout n=lane&31, m=(r&3)+8*(r>>2)+4*(lane>>5) ----
    float* Hw = Hsh + wave * (32 * HS);
    #pragma unroll
    for (int r = 0; r < 16; ++r) {
        const int mr = (r & 3) + 8 * (r >> 2) + 4 * (lane >> 5);
        Hw[mr * HS + (lane & 31)]      = acc0[r];
        Hw[mr * HS + (lane & 31) + 32] = acc1[r];
    }
    __syncthreads();  // (wave-local would suffice; cheap safety)

    // ---- layers 2+3 in fp32: lane handles column m=lane&31 (upper half duplicates) ----
    const int mc = lane & 31;
    const float* Hr = Hw + mc * HS;
    float h2[D2];
    #pragma unroll
    for (int e = 0; e < D2; ++e) h2[e] = b2[e];
    #pragma unroll 8
    for (int d = 0; d < D1; ++d) {
        float h = Hr[d] + b1[d];
        h = h > 0.f ? h : 0.f;
        #pragma unroll
        for (int e = 0; e < D2; ++e)
            h2[e] = fmaf(h, W2[d * D2 + e], h2[e]);
    }
    float o = b3[0];
    #pragma unroll
    for (int e = 0; e < D2; ++e) {
        float h = h2[e] > 0.f ? h2[e] : 0.f;
        o = fmaf(h, W3[e], o);
    }
    if (lane < 32)
        out[mBase + wave * 32 + mc] = o;
}

extern "C" void kernel_launch(void* const* d_in, const int* in_sizes, int n_in,
                              void* d_out, int out_size, void* d_ws, size_t ws_size,
                              hipStream_t stream) {
    const float* inputs = (const float*)d_in[0];
    const float* W1     = (const float*)d_in[1];
    const float* b1     = (const float*)d_in[2];
    const float* W2     = (const float*)d_in[3];
    const float* b2     = (const float*)d_in[4];
    const float* W3     = (const float*)d_in[5];
    const float* b3     = (const float*)d_in[6];
    float* out = (float*)d_out;

    dim3 block(256);
    dim3 grid(BA / MB);  // 1024 blocks
    mlp3_mfma<<<grid, block, 0, stream>>>(inputs, W1, b1, W2, b2, W3, b3, out);
}